// Round 1
// baseline (209.589 us; speedup 1.0000x reference)
//
#include <hip/hip_runtime.h>

// DeepPatchEncoder collapses to:
//   out[b, n0, d] = X[b, y, x, c] + bias[n0, d]
// where bias[n0,d] = pos_emb[n0,d] + BN(conv2x2s2(pos_emb-as-image))[n1, y%8, x%8, c]
// (y,x,c) <-> (n0,d) via n0=(y/16)*14+(x/16), d=((y%16)*16+(x%16))*3+c.
// bias is batch-independent -> precompute into d_ws (602 KB), then do a
// memory-bound permuted add over 128*196*768 floats.

#define TOT_BIAS (3 * 8 * 8 * 784)          // 150,528
#define TOT_OUT (128 * 196 * 768)           // 19,267,584
#define TOT_OUT4 (TOT_OUT / 4)              // 4,816,896

__global__ void __launch_bounds__(256) compute_bias_kernel(
    const float* __restrict__ pos_emb,   // [196, 768]
    const float* __restrict__ conv_w,    // [2,2,196,784] HWIO
    const float* __restrict__ bn_gamma,  // [784]
    const float* __restrict__ bn_beta,
    const float* __restrict__ bn_mean,
    const float* __restrict__ bn_var,
    float* __restrict__ bias)            // [196, 768] (d_ws)
{
    int idx = blockIdx.x * blockDim.x + threadIdx.x;
    if (idx >= TOT_BIAS) return;
    // thread layout: consecutive threads -> consecutive output channel o
    // (coalesced conv_w loads; pos_emb index is wave-uniform -> broadcast)
    int o = idx % 784;
    int t = idx / 784;
    int j = t % 8;        // output col (qx)
    t /= 8;
    int i = t % 8;        // output row (qy)
    int c = t / 8;        // "batch" = image channel 0..2

    // pos_img[c, py, px, n] = pos_emb[n, (py*16+px)*3 + c]
    // pos_c[c,i,j,o] = sum_{di,dj,n} pos_img[c, 2i+di, 2j+dj, n] * w[di,dj,n,o]
    float sum = 0.f;
#pragma unroll
    for (int di = 0; di < 2; ++di) {
#pragma unroll
        for (int dj = 0; dj < 2; ++dj) {
            const int y16 = 2 * i + di;
            const int x16 = 2 * j + dj;
            const int pe_off = (y16 * 16 + x16) * 3 + c;
            const float* __restrict__ w = conv_w + (size_t)((di * 2 + dj) * 196) * 784 + o;
            for (int n = 0; n < 196; ++n) {
                sum += pos_emb[n * 768 + pe_off] * w[(size_t)n * 784];
            }
        }
    }

    // inference BatchNorm, eps = 1e-3 (Keras default)
    const float scale = bn_gamma[o] / sqrtf(bn_var[o] + 1e-3f);
    const float val = (sum - bn_mean[o]) * scale + bn_beta[o];

    // scatter pos_new[o, i, j, c] into (n0, d) coordinates, fused with pos_emb add
    const int y8 = o / 28, x8 = o % 28;
    const int y = y8 * 8 + i;
    const int x = x8 * 8 + j;
    const int n0 = (y >> 4) * 14 + (x >> 4);
    const int py = y & 15, px = x & 15;
    const int d = (py * 16 + px) * 3 + c;
    bias[n0 * 768 + d] = pos_emb[n0 * 768 + d] + val;
}

__global__ void __launch_bounds__(256) add_bias_kernel(
    const float* __restrict__ X,      // [128, 224, 224, 3]
    const float* __restrict__ bias,   // [196, 768]
    float* __restrict__ out)          // [128, 196, 768]
{
    int tid = blockIdx.x * blockDim.x + threadIdx.x;
    if (tid >= TOT_OUT4) return;
    const int flat = tid * 4;
    const int b = flat / 150528;           // 196*768
    const int rem = flat - b * 150528;
    const int n0 = rem / 768;
    const int d = rem - n0 * 768;
    const int py = d / 48;                 // 16*3
    const int r = d - py * 48;
    const int y = (n0 / 14) * 16 + py;
    const int xcol = (n0 % 14) * 48 + r;   // (x*3 + c) within the row
    // all offsets are multiples of 4 floats -> float4 safe
    const float4 xv = *reinterpret_cast<const float4*>(X + (size_t)b * 150528 + y * 672 + xcol);
    const float4 bv = *reinterpret_cast<const float4*>(bias + rem);
    float4 ov;
    ov.x = xv.x + bv.x;
    ov.y = xv.y + bv.y;
    ov.z = xv.z + bv.z;
    ov.w = xv.w + bv.w;
    *reinterpret_cast<float4*>(out + flat) = ov;
}

extern "C" void kernel_launch(void* const* d_in, const int* in_sizes, int n_in,
                              void* d_out, int out_size, void* d_ws, size_t ws_size,
                              hipStream_t stream) {
    const float* X        = (const float*)d_in[0];
    const float* pos_emb  = (const float*)d_in[1];
    const float* conv_w   = (const float*)d_in[2];
    const float* bn_gamma = (const float*)d_in[3];
    const float* bn_beta  = (const float*)d_in[4];
    const float* bn_mean  = (const float*)d_in[5];
    const float* bn_var   = (const float*)d_in[6];
    float* out  = (float*)d_out;
    float* bias = (float*)d_ws;   // 196*768 floats = 602,112 bytes

    compute_bias_kernel<<<(TOT_BIAS + 255) / 256, 256, 0, stream>>>(
        pos_emb, conv_w, bn_gamma, bn_beta, bn_mean, bn_var, bias);
    add_bias_kernel<<<(TOT_OUT4 + 255) / 256, 256, 0, stream>>>(X, bias, out);
}

// Round 2
// 173.891 us; speedup vs baseline: 1.2053x; 1.2053x over previous
//
#include <hip/hip_runtime.h>

// DeepPatchEncoder collapses to:
//   out[b, n0, d] = X[b, y, x, c] + bias[n0, d]
// where bias[n0,d] = pos_emb[n0,d] + BN(conv2x2s2(pos_emb-as-image))[n1, y%8, x%8, c]
// bias is batch-independent -> precompute into d_ws (602 KB), then do a
// memory-bound permuted add over 128*196*768 floats.
//
// R2: compute_bias restructured as tiled reduction:
//   block = (tap 0..3) x (o_lane 0..63), m-group of 4 rows staged in LDS
//   transposed (At[k][m]) so inner loop = 1 coalesced w load + 1 ds_read_b128
//   + 4 FMAs. R1 version was latency-bound at 68 us (208 cyc/iter, 23% occ).

#define TOT_OUT (128 * 196 * 768)           // 19,267,584
#define TOT_OUT4 (TOT_OUT / 4)              // 4,816,896

__global__ void __launch_bounds__(256) compute_bias_v2(
    const float* __restrict__ pos_emb,   // [196, 768]
    const float* __restrict__ conv_w,    // [2,2,196,784] HWIO -> viewed [784, 784]
    const float* __restrict__ bn_gamma,  // [784]
    const float* __restrict__ bn_beta,
    const float* __restrict__ bn_mean,
    const float* __restrict__ bn_var,
    float* __restrict__ bias)            // [196, 768] (d_ws)
{
    __shared__ float At[784 * 4];        // A transposed: At[k][ml], ml = 4 m-rows
    __shared__ float4 red[4][64];        // tap-reduction buffer

    const int mg = blockIdx.x;           // 0..47: (c, i, jhalf)
    const int ot = blockIdx.y;           // 0..12: o-tile of 64
    const int c  = mg >> 4;
    const int i  = (mg & 15) >> 1;
    const int j0 = (mg & 1) * 4;
    const int t  = threadIdx.x;

    // Stage A into LDS, transposed. A[m][k] = pos_img[c, 2i+di, 2(j0+ml)+dj, n]
    // = pos_emb[n, ((2i+di)*16 + 2(j0+ml)+dj)*3 + c], k = (di*2+dj)*196 + n.
    for (int idx = t; idx < 784 * 4; idx += 256) {
        const int ml  = idx & 3;
        const int k   = idx >> 2;
        const int tap = k / 196;
        const int n   = k - tap * 196;
        const int di = tap >> 1, dj = tap & 1;
        const int y16 = 2 * i + di;
        const int x16 = 2 * (j0 + ml) + dj;
        At[idx] = pos_emb[n * 768 + (y16 * 16 + x16) * 3 + c];
    }
    __syncthreads();

    const int o_lane = t & 63;
    const int tap    = t >> 6;
    const int o      = ot * 64 + o_lane;
    const int o_c    = o < 784 ? o : 783;   // clamp: keeps w loads in-bounds
    const float* __restrict__ wp = conv_w + (size_t)(tap * 196) * 784 + o_c;
    const float4* __restrict__ At4 = reinterpret_cast<const float4*>(At) + tap * 196;

    float4 acc = {0.f, 0.f, 0.f, 0.f};
#pragma unroll 4
    for (int n = 0; n < 196; ++n) {
        const float  wv = wp[n * 784];
        const float4 a  = At4[n];
        acc.x += a.x * wv;
        acc.y += a.y * wv;
        acc.z += a.z * wv;
        acc.w += a.w * wv;
    }
    red[tap][o_lane] = acc;
    __syncthreads();

    if (t < 64) {
        const int oo = ot * 64 + t;
        if (oo < 784) {
            const float4 r0 = red[0][t], r1 = red[1][t], r2 = red[2][t], r3 = red[3][t];
            float sum[4];
            sum[0] = r0.x + r1.x + r2.x + r3.x;
            sum[1] = r0.y + r1.y + r2.y + r3.y;
            sum[2] = r0.z + r1.z + r2.z + r3.z;
            sum[3] = r0.w + r1.w + r2.w + r3.w;
            const float scale = bn_gamma[oo] * rsqrtf(bn_var[oo] + 1e-3f);
            const float mb = bn_mean[oo], bb = bn_beta[oo];
            const int y8 = oo / 28, x8 = oo % 28;
#pragma unroll
            for (int ml = 0; ml < 4; ++ml) {
                const float val = (sum[ml] - mb) * scale + bb;
                const int j = j0 + ml;
                const int y = y8 * 8 + i;
                const int x = x8 * 8 + j;
                const int n0 = (y >> 4) * 14 + (x >> 4);
                const int d  = ((y & 15) * 16 + (x & 15)) * 3 + c;
                bias[n0 * 768 + d] = pos_emb[n0 * 768 + d] + val;
            }
        }
    }
}

__global__ void __launch_bounds__(256) add_bias_kernel(
    const float* __restrict__ X,      // [128, 224, 224, 3]
    const float* __restrict__ bias,   // [196, 768]
    float* __restrict__ out)          // [128, 196, 768]
{
    int tid = blockIdx.x * blockDim.x + threadIdx.x;
    if (tid >= TOT_OUT4) return;
    const int flat = tid * 4;
    const int b = flat / 150528;           // 196*768
    const int rem = flat - b * 150528;
    const int n0 = rem / 768;
    const int d = rem - n0 * 768;
    const int py = d / 48;                 // 16*3
    const int r = d - py * 48;
    const int y = (n0 / 14) * 16 + py;
    const int xcol = (n0 % 14) * 48 + r;   // (x*3 + c) within the row
    // all offsets are multiples of 4 floats -> float4 safe
    const float4 xv = *reinterpret_cast<const float4*>(X + (size_t)b * 150528 + y * 672 + xcol);
    const float4 bv = *reinterpret_cast<const float4*>(bias + rem);
    float4 ov;
    ov.x = xv.x + bv.x;
    ov.y = xv.y + bv.y;
    ov.z = xv.z + bv.z;
    ov.w = xv.w + bv.w;
    *reinterpret_cast<float4*>(out + flat) = ov;
}

extern "C" void kernel_launch(void* const* d_in, const int* in_sizes, int n_in,
                              void* d_out, int out_size, void* d_ws, size_t ws_size,
                              hipStream_t stream) {
    const float* X        = (const float*)d_in[0];
    const float* pos_emb  = (const float*)d_in[1];
    const float* conv_w   = (const float*)d_in[2];
    const float* bn_gamma = (const float*)d_in[3];
    const float* bn_beta  = (const float*)d_in[4];
    const float* bn_mean  = (const float*)d_in[5];
    const float* bn_var   = (const float*)d_in[6];
    float* out  = (float*)d_out;
    float* bias = (float*)d_ws;   // 196*768 floats = 602,112 bytes

    dim3 bias_grid(48, 13);       // 48 m-groups x 13 o-tiles of 64
    compute_bias_v2<<<bias_grid, 256, 0, stream>>>(
        pos_emb, conv_w, bn_gamma, bn_beta, bn_mean, bn_var, bias);
    add_bias_kernel<<<(TOT_OUT4 + 255) / 256, 256, 0, stream>>>(X, bias, out);
}